// Round 5
// baseline (547.138 us; speedup 1.0000x reference)
//
#include <hip/hip_runtime.h>
#include <math.h>

#define NN  50000
#define FIN 512
#define HH1 500
#define HH2 100
#define NC  16
#define NE  800000
#define KD  512            // K-pad for layers 1/2

typedef __attribute__((ext_vector_type(4))) float    f32x4;
typedef __attribute__((ext_vector_type(4))) _Float16 f16x4;
typedef __attribute__((ext_vector_type(8))) _Float16 f16x8;
typedef __attribute__((ext_vector_type(8))) unsigned short u16x8;
typedef __attribute__((ext_vector_type(4))) unsigned short u16x4;

// ---------------- CSR build ----------------

__global__ void zero2_k(int* a, int* b) {
    int i = blockIdx.x * blockDim.x + threadIdx.x;
    if (i < NN) { a[i] = 0; b[i] = 0; }
}

__global__ void hist_k(const int* __restrict__ rows, int* __restrict__ rowcnt) {
    int i = blockIdx.x * blockDim.x + threadIdx.x;
    if (i < NE) atomicAdd(&rowcnt[rows[i]], 1);
}

__global__ void dinv_k(const int* __restrict__ rowcnt, float* __restrict__ dinv) {
    int i = blockIdx.x * blockDim.x + threadIdx.x;
    if (i < NN) dinv[i] = rsqrtf((float)(rowcnt[i] + 1));   // +1 self-loop
}

// hierarchical scan: 49 blocks x 1024 -> 1-wave scan of block sums -> add
__global__ __launch_bounds__(1024) void scan1_k(const int* __restrict__ cnt,
                                                int* __restrict__ excl,
                                                int* __restrict__ bsum) {
    __shared__ int s[1024];
    int t = threadIdx.x;
    int i = blockIdx.x * 1024 + t;
    int v = (i < NN) ? cnt[i] : 0;
    s[t] = v;
    __syncthreads();
    #pragma unroll
    for (int off = 1; off < 1024; off <<= 1) {
        int add = (t >= off) ? s[t - off] : 0;
        __syncthreads();
        s[t] += add;
        __syncthreads();
    }
    if (i < NN) excl[i] = s[t] - v;
    if (t == 1023) bsum[blockIdx.x] = s[1023];
}

__global__ void scan2_k(int* bsum, int nb) {   // 1 block, 64 threads
    int lane = threadIdx.x;
    int orig = (lane < nb) ? bsum[lane] : 0;
    int v = orig;
    #pragma unroll
    for (int off = 1; off < 64; off <<= 1) {
        int u = __shfl_up(v, off, 64);
        if (lane >= off) v += u;
    }
    if (lane < nb) bsum[lane] = v - orig;      // exclusive
}

__global__ void scan3_k(const int* __restrict__ excl, const int* __restrict__ bsum,
                        int* __restrict__ ptr) {
    int i = blockIdx.x * 256 + threadIdx.x;
    if (i < NN) ptr[i] = excl[i] + bsum[i >> 10];
}

// fused (col, w) edge record: one 8B store per edge instead of two scattered 4B
__global__ void scatter_k(const int* __restrict__ rows, const int* __restrict__ cols,
                          const float* __restrict__ dinv,
                          const int* __restrict__ row_ptr, int* __restrict__ fill,
                          int2* __restrict__ cw) {
    int e = blockIdx.x * blockDim.x + threadIdx.x;
    if (e >= NE) return;
    int r = rows[e], c = cols[e];
    int pos = row_ptr[r] + atomicAdd(&fill[r], 1);
    cw[pos] = make_int2(c, __float_as_int(dinv[r] * dinv[c]));
}

// ---------------- fused W pre-transpose to fp16 ----------------
// Wt1[512][512], Wt2[128][512], Wt3[128][128], zero-padded, n-major.

#define R1 (512 * 512)
#define R2 (128 * 512)
#define R3 (128 * 128)

__global__ void wconv3_k(const float* __restrict__ W1, const float* __restrict__ W2,
                         const float* __restrict__ W3, _Float16* __restrict__ Wt1,
                         _Float16* __restrict__ Wt2, _Float16* __restrict__ Wt3)
{
    int idx = blockIdx.x * 256 + threadIdx.x;
    if (idx < R1) {
        int n_ = idx >> 9, kk = idx & 511;
        float v = (n_ < HH1) ? W1[(size_t)kk * HH1 + n_] : 0.0f;
        Wt1[idx] = (_Float16)v;
    } else if (idx < R1 + R2) {
        int j = idx - R1;
        int n_ = j >> 9, kk = j & 511;
        float v = (kk < HH1 && n_ < HH2) ? W2[(size_t)kk * HH2 + n_] : 0.0f;
        Wt2[j] = (_Float16)v;
    } else if (idx < R1 + R2 + R3) {
        int j = idx - R1 - R2;
        int n_ = j >> 7, kk = j & 127;
        float v = (kk < HH2 && n_ < NC) ? W3[(size_t)kk * NC + n_] : 0.0f;
        Wt3[j] = (_Float16)v;
    }
}

// ---------------- async global->LDS helper ----------------

typedef unsigned int u32g;

__device__ __forceinline__ void g2l16(const void* g, void* l) {
    __builtin_amdgcn_global_load_lds(
        (const __attribute__((address_space(1))) u32g*)g,
        (__attribute__((address_space(3))) u32g*)l, 16, 0, 0);
}

// ---------------- GEMM1: fp32 A direct, 64x512 tile ----------------
// One block = 64 rows x all 512 cols (A read exactly ONCE, no cvtx pass).
// A is reg-staged (T14 split): global_load_dwordx4 issued TWO K-steps ahead,
// fp32->fp16 convert + ds_write just before the barrier. LDS bytes produced
// are identical to the R4 path (same swizzle involution, same RNE convert),
// so the ds_read side and all numerics are unchanged.
// B (Wt1, 0.5MB, L2-resident) staged with global_load_lds 1 step ahead.
// 32 MFMA per wave per barrier (2x R4's ratio). LDS 72KB -> 2 blocks/CU.

__global__ __launch_bounds__(256, 2) void gemm1_k(
    const float* __restrict__ A, const _Float16* __restrict__ Wt,
    const float* __restrict__ bias, _Float16* __restrict__ Cb, int n)
{
    __shared__ __align__(16) _Float16 As[2][64 * 32];    // 4KB  x2
    __shared__ __align__(16) _Float16 Bs[2][512 * 32];   // 32KB x2

    int tid  = threadIdx.x;
    int lane = tid & 63;
    int w    = tid >> 6;
    int lr = lane & 15, q = lane >> 4;
    int row0 = blockIdx.x * 64;

    f32x4 acc[4][8];
    #pragma unroll
    for (int i = 0; i < 4; i++)
        #pragma unroll
        for (int j = 0; j < 8; j++) acc[i][j] = (f32x4){0.f, 0.f, 0.f, 0.f};

    // A staging: 64 rows x 4 fp16-16B-units; this thread owns one unit.
    int arr = tid >> 2, ac8 = tid & 3;
    int ac8s = ac8 ^ ((arr >> 1) & 3);                 // pre-swizzled source unit
    int gr = row0 + arr; if (gr >= n) gr = n - 1;      // clamp; row never stored
    const float* asrc = A + (size_t)gr * 512 + ac8s * 8;

    float4 pav[2][2];   // [parity][lo/hi float4]

    auto aload = [&](int kt, int par) {
        pav[par][0] = *(const float4*)(asrc + kt);
        pav[par][1] = *(const float4*)(asrc + kt + 4);
    };
    auto astore = [&](int bf, int par) {
        float4 v0 = pav[par][0], v1 = pav[par][1];
        f16x8 h = {(_Float16)v0.x, (_Float16)v0.y, (_Float16)v0.z, (_Float16)v0.w,
                   (_Float16)v1.x, (_Float16)v1.y, (_Float16)v1.z, (_Float16)v1.w};
        *(f16x8*)&As[bf][tid * 8] = h;
    };
    auto bstage = [&](int kt, int bf) {
        #pragma unroll
        for (int i = 0; i < 8; i++) {
            int id = i * 256 + tid;
            int rr = id >> 2, c8 = id & 3;
            int c8s = c8 ^ ((rr >> 1) & 3);
            g2l16(Wt + (size_t)rr * 512 + kt + c8s * 8, &Bs[bf][id * 8]);
        }
    };

    // prologue: A(0),A(1) in flight; stage A(0)+B(0); publish.
    aload(0, 0);
    aload(32, 1);
    bstage(0, 0);
    astore(0, 0);
    __syncthreads();

    #pragma unroll
    for (int step = 0; step < 16; step++) {
        int bf = step & 1;
        int par = step & 1;
        if (step + 2 < 16) aload((step + 2) * 32, par);      // A: 2 ahead
        if (step + 1 < 16) bstage((step + 1) * 32, bf ^ 1);  // B: 1 ahead

        f16x8 a[4], b[8];
        #pragma unroll
        for (int t = 0; t < 4; t++) {
            int row = t * 16 + lr;
            a[t] = *(const f16x8*)&As[bf][(row * 4 + (q ^ ((row >> 1) & 3))) * 8];
        }
        #pragma unroll
        for (int t = 0; t < 8; t++) {
            int row = w * 128 + t * 16 + lr;
            b[t] = *(const f16x8*)&Bs[bf][(row * 4 + (q ^ ((row >> 1) & 3))) * 8];
        }
        #pragma unroll
        for (int ti = 0; ti < 4; ti++)
            #pragma unroll
            for (int tj = 0; tj < 8; tj++)
                acc[ti][tj] = __builtin_amdgcn_mfma_f32_16x16x32_f16(
                    a[ti], b[tj], acc[ti][tj], 0, 0, 0);

        if (step + 1 < 16) astore(bf ^ 1, par ^ 1);          // convert+write A(t+1)
        __syncthreads();
        (void)bf;
    }

    // epilogue: chunk-major fp16 C  [col>>8][row][col&255]
    #pragma unroll
    for (int ti = 0; ti < 4; ti++) {
        #pragma unroll
        for (int tj = 0; tj < 8; tj++) {
            int col = w * 128 + tj * 16 + lr;
            bool valid = col < HH1;
            float bv = valid ? bias[col] : 0.0f;
            size_t cbase = (size_t)(col >> 8) * ((size_t)NN * 256) + (col & 255);
            #pragma unroll
            for (int p = 0; p < 4; p++) {
                int row = row0 + ti * 16 + q * 4 + p;
                if (row < n) {
                    float v = valid ? (acc[ti][tj][p] + bv) : 0.0f;
                    Cb[cbase + (size_t)row * 256] = (_Float16)v;
                }
            }
        }
    }
}

// ---------------- fp16 MFMA GEMM via global_load_lds (layers 2/3) ----------

template<int BCOLS, int COUT, int KK>
__global__ __launch_bounds__(256, 3) void gemm_lds_k(
    const _Float16* __restrict__ A,    // [n][KK] fp16
    const _Float16* __restrict__ Wt,   // [.][KK] fp16, n-major
    const float* __restrict__ bias, _Float16* __restrict__ Cb,
    int mpad, int n, int m)
{
    constexpr int NBF   = BCOLS / 64;   // B fragments per wave
    constexpr int WC    = BCOLS / 4;    // cols per wave
    constexpr int NSTEP = KK / 32;

    __shared__ __align__(16) _Float16 As[2][64 * 32];
    __shared__ __align__(16) _Float16 Bs[2][BCOLS * 32];

    int tid  = threadIdx.x;
    int lane = tid & 63;
    int w    = tid >> 6;
    int lr = lane & 15, q = lane >> 4;
    int row0 = blockIdx.x * 64;
    int col0 = blockIdx.y * BCOLS;

    f32x4 acc[4][NBF];
    #pragma unroll
    for (int i = 0; i < 4; i++)
        #pragma unroll
        for (int j = 0; j < NBF; j++) acc[i][j] = (f32x4){0.f, 0.f, 0.f, 0.f};

    auto stage = [&](int kt, int bf) {
        {   // A tile: 64 rows x 32 cols = 256 x 16B
            int rr = tid >> 2, c8 = tid & 3;
            int c8s = c8 ^ ((rr >> 1) & 3);             // pre-swizzled source
            int gr = row0 + rr; if (gr >= n) gr = n - 1; // clamp; row never stored
            g2l16(A + (size_t)gr * KK + kt + c8s * 8, &As[bf][tid * 8]);
        }
        #pragma unroll
        for (int i = 0; i < NBF; i++) {                 // B tile: BCOLS x 32
            int idx = i * 256 + tid;
            int rr = idx >> 2, c8 = idx & 3;
            int c8s = c8 ^ ((rr >> 1) & 3);
            g2l16(Wt + (size_t)(col0 + rr) * KK + kt + c8s * 8, &Bs[bf][idx * 8]);
        }
    };

    stage(0, 0);
    int bf = 0;
    #pragma unroll
    for (int step = 0; step < NSTEP; step++) {
        __syncthreads();                   // drains gload_lds for buf bf
        if (step + 1 < NSTEP) stage((step + 1) * 32, bf ^ 1);

        f16x8 a[4], b[NBF];
        #pragma unroll
        for (int t = 0; t < 4; t++) {
            int row = t * 16 + lr;
            a[t] = *(const f16x8*)&As[bf][(row * 4 + (q ^ ((row >> 1) & 3))) * 8];
        }
        #pragma unroll
        for (int t = 0; t < NBF; t++) {
            int row = w * WC + t * 16 + lr;
            b[t] = *(const f16x8*)&Bs[bf][(row * 4 + (q ^ ((row >> 1) & 3))) * 8];
        }
        #pragma unroll
        for (int ti = 0; ti < 4; ti++)
            #pragma unroll
            for (int tj = 0; tj < NBF; tj++)
                acc[ti][tj] = __builtin_amdgcn_mfma_f32_16x16x32_f16(
                    a[ti], b[tj], acc[ti][tj], 0, 0, 0);
        bf ^= 1;
    }

    #pragma unroll
    for (int ti = 0; ti < 4; ti++) {
        #pragma unroll
        for (int tj = 0; tj < NBF; tj++) {
            int col = col0 + w * WC + tj * 16 + lr;
            if (COUT == 0 && col >= mpad) continue;
            bool valid = col < m;
            float bv = valid ? bias[col] : 0.0f;
            #pragma unroll
            for (int p = 0; p < 4; p++) {
                int row = row0 + ti * 16 + q * 4 + p;
                if (row < n) {
                    float v = valid ? (acc[ti][tj][p] + bv) : 0.0f;
                    if (COUT == 1) {
                        size_t addr = (size_t)(col >> 8) * ((size_t)NN * 256)
                                    + (size_t)row * 256 + (col & 255);
                        Cb[addr] = (_Float16)v;
                    } else {
                        Cb[(size_t)row * mpad + col] = (_Float16)v;
                    }
                }
            }
        }
    }
}

// ---------------- fp16 mixed-precision FMA helpers ----------------

__device__ __forceinline__ void fma_mix8(float* acc, u16x8 v, float w) {
    union { u16x8 u; unsigned int d[4]; } t; t.u = v;
    #pragma unroll
    for (int k = 0; k < 4; k++) {
        asm("v_fma_mix_f32 %0, %1, %2, %0 op_sel:[0,0,0] op_sel_hi:[1,0,0]"
            : "+v"(acc[2 * k]) : "v"(t.d[k]), "v"(w));
        asm("v_fma_mix_f32 %0, %1, %2, %0 op_sel:[1,0,0] op_sel_hi:[1,0,0]"
            : "+v"(acc[2 * k + 1]) : "v"(t.d[k]), "v"(w));
    }
}

__device__ __forceinline__ void fma_mix4(float* acc, u16x4 v, float w) {
    union { u16x4 u; unsigned int d[2]; } t; t.u = v;
    #pragma unroll
    for (int k = 0; k < 2; k++) {
        asm("v_fma_mix_f32 %0, %1, %2, %0 op_sel:[0,0,0] op_sel_hi:[1,0,0]"
            : "+v"(acc[2 * k]) : "v"(t.d[k]), "v"(w));
        asm("v_fma_mix_f32 %0, %1, %2, %0 op_sel:[1,0,0] op_sel_hi:[1,0,0]"
            : "+v"(acc[2 * k + 1]) : "v"(t.d[k]), "v"(w));
    }
}

// ---------------- SpMM L1: feature-split gather (2 passes x 256 features) ----

__global__ __launch_bounds__(256) void spmm_f16_256_k(
    const int* __restrict__ row_ptr, const int* __restrict__ rowcnt,
    const int2* __restrict__ cw, const float* __restrict__ dinv,
    const _Float16* __restrict__ hc,   // chunk base: [NN][256]
    _Float16* __restrict__ outh, int fbase)
{
    int r = blockIdx.x * 4 + (threadIdx.x >> 6);
    int lane = threadIdx.x & 63;
    if (r >= NN) return;

    const u16x4* h4 = (const u16x4*)hc;   // row stride = 64 vec4

    float acc[4];
    #pragma unroll
    for (int i = 0; i < 4; i++) acc[i] = 0.f;

    float d = dinv[r];
    fma_mix4(acc, h4[(size_t)r * 64 + lane], d * d);   // self loop

    int beg = row_ptr[r], cnt = rowcnt[r];
    for (int base = 0; base < cnt; base += 64) {
        int m = (cnt - base < 64) ? (cnt - base) : 64;
        int2 vc = (lane < m) ? cw[beg + base + lane] : make_int2(0, 0);
        int P = (m + 7) & ~7;
        for (int j = 0; j < P; j += 8) {
            u16x4 vv[8]; float wl[8];
            #pragma unroll
            for (int u = 0; u < 8; u++) {
                int c  = __builtin_amdgcn_readlane(vc.x, j + u);
                int wb = __builtin_amdgcn_readlane(vc.y, j + u);
                wl[u] = __int_as_float(wb);
                vv[u] = h4[(size_t)c * 64 + lane];
            }
            #pragma unroll
            for (int u = 0; u < 8; u++) fma_mix4(acc, vv[u], wl[u]);
        }
    }

    int f0 = fbase + lane * 4;
    f16x4 o;
    #pragma unroll
    for (int i = 0; i < 4; i++)
        o[i] = (_Float16)((f0 + i < HH1) ? tanhf(acc[i]) : 0.0f);
    __builtin_nontemporal_store(o, (f16x4*)(outh + (size_t)r * KD + f0));
}

// ---------------- SpMM L2: fp16 gather (stride 128) -> fp16 out (stride 128) --

__global__ __launch_bounds__(256) void spmm_f16_100_k(
    const int* __restrict__ row_ptr, const int* __restrict__ rowcnt,
    const int2* __restrict__ cw, const float* __restrict__ dinv,
    const _Float16* __restrict__ hb, _Float16* __restrict__ outh)
{
    int r = blockIdx.x * 16 + (threadIdx.x >> 4);
    int lane = threadIdx.x & 15;
    if (r >= NN) return;

    const u16x8* h8 = (const u16x8*)hb;   // row stride = 16 vec8

    float acc[8];
    #pragma unroll
    for (int i = 0; i < 8; i++) acc[i] = 0.f;

    float d = dinv[r];
    fma_mix8(acc, h8[(size_t)r * 16 + lane], d * d);

    int beg = row_ptr[r], cnt = rowcnt[r];
    int j = 0;
    for (; j + 7 < cnt; j += 8) {
        int2  e[8];
        u16x8 v[8];
        #pragma unroll
        for (int u = 0; u < 8; u++) e[u] = cw[beg + j + u];
        #pragma unroll
        for (int u = 0; u < 8; u++) v[u] = h8[(size_t)e[u].x * 16 + lane];
        #pragma unroll
        for (int u = 0; u < 8; u++) fma_mix8(acc, v[u], __int_as_float(e[u].y));
    }
    for (; j < cnt; j++) {
        int2 e = cw[beg + j];
        fma_mix8(acc, h8[(size_t)e.x * 16 + lane], __int_as_float(e.y));
    }

    int f0 = lane * 8;
    f16x8 o;
    #pragma unroll
    for (int i = 0; i < 8; i++)
        o[i] = (_Float16)((f0 + i < HH2) ? tanhf(acc[i]) : 0.0f);
    __builtin_nontemporal_store(o, (f16x8*)(outh + (size_t)r * 128 + f0));
}

// ---------------- SpMM L3: fp16 gather (stride 16) -> fp32 out (stride 16) ----

__global__ __launch_bounds__(256) void spmm3h_k(
    const int* __restrict__ row_ptr, const int* __restrict__ rowcnt,
    const int2* __restrict__ cw, const float* __restrict__ dinv,
    const _Float16* __restrict__ hb, float* __restrict__ out)
{
    int r = blockIdx.x * 128 + (threadIdx.x >> 1);
    int lane = threadIdx.x & 1;
    if (r >= NN) return;

    const u16x8* h8 = (const u16x8*)hb;   // row stride = 2 vec8

    float acc[8];
    #pragma unroll
    for (int i = 0; i < 8; i++) acc[i] = 0.f;

    float d = dinv[r];
    fma_mix8(acc, h8[(size_t)r * 2 + lane], d * d);

    int beg = row_ptr[r], cnt = rowcnt[r];
    int j = 0;
    for (; j + 3 < cnt; j += 4) {
        int2  e0 = cw[beg + j],     e1 = cw[beg + j + 1];
        int2  e2 = cw[beg + j + 2], e3 = cw[beg + j + 3];
        u16x8 v0 = h8[(size_t)e0.x * 2 + lane];
        u16x8 v1 = h8[(size_t)e1.x * 2 + lane];
        u16x8 v2 = h8[(size_t)e2.x * 2 + lane];
        u16x8 v3 = h8[(size_t)e3.x * 2 + lane];
        fma_mix8(acc, v0, __int_as_float(e0.y));
        fma_mix8(acc, v1, __int_as_float(e1.y));
        fma_mix8(acc, v2, __int_as_float(e2.y));
        fma_mix8(acc, v3, __int_as_float(e3.y));
    }
    for (; j < cnt; j++) {
        int2 e = cw[beg + j];
        fma_mix8(acc, h8[(size_t)e.x * 2 + lane], __int_as_float(e.y));
    }

    float* o = out + (size_t)r * NC + lane * 8;
    f32x4 a0 = {acc[0], acc[1], acc[2], acc[3]};
    f32x4 a1 = {acc[4], acc[5], acc[6], acc[7]};
    __builtin_nontemporal_store(a0, (f32x4*)o);
    __builtin_nontemporal_store(a1, (f32x4*)(o + 4));
}

// final: tanh then softmax over 16 classes, one thread per row
__global__ void tanh_softmax_k(const float* __restrict__ in, float* __restrict__ out) {
    int r = blockIdx.x * blockDim.x + threadIdx.x;
    if (r >= NN) return;
    float v[NC];
    float mx = -1e30f;
    #pragma unroll
    for (int j = 0; j < NC; j++) {
        v[j] = tanhf(in[r * NC + j]);
        mx = fmaxf(mx, v[j]);
    }
    float s = 0.0f;
    #pragma unroll
    for (int j = 0; j < NC; j++) { v[j] = expf(v[j] - mx); s += v[j]; }
    float inv = 1.0f / s;
    #pragma unroll
    for (int j = 0; j < NC; j++) out[r * NC + j] = v[j] * inv;
}

// ---------------- launch ----------------

extern "C" void kernel_launch(void* const* d_in, const int* in_sizes, int n_in,
                              void* d_out, int out_size, void* d_ws, size_t ws_size,
                              hipStream_t stream)
{
    const float* x  = (const float*)d_in[0];
    const int*   ei = (const int*)d_in[1];
    const float* W1 = (const float*)d_in[2];
    const float* b1 = (const float*)d_in[3];
    const float* W2 = (const float*)d_in[4];
    const float* b2 = (const float*)d_in[5];
    const float* W3 = (const float*)d_in[6];
    const float* b3 = (const float*)d_in[7];
    float* out = (float*)d_out;

    const int* rows = ei;
    const int* cols = ei + NE;

    char* p = (char*)d_ws;
    float*     dinv    = (float*)p;     p += (size_t)NN * 4;
    int*       rowcnt  = (int*)p;       p += (size_t)NN * 4;
    int*       row_ptr = (int*)p;       p += (size_t)NN * 4;
    int*       fill    = (int*)p;       p += (size_t)NN * 4;
    int*       excl    = (int*)p;       p += (size_t)NN * 4;
    int*       bsum    = (int*)p;       p += (size_t)256 * 4;
    int2*      cw      = (int2*)p;      p += (size_t)NE * 8;    // fused (col, w)
    float*     B3      = (float*)p;     p += (size_t)NN * NC * 4;   // SpMM3 out
    _Float16*  A1h     = (_Float16*)p;  p += (size_t)NN * KD * 2;   // GEMM1 out, chunked [2][NN][256]
    _Float16*  h1h     = (_Float16*)p;  p += (size_t)NN * KD * 2;   // SpMM1 out, linear [NN][512]
    _Float16*  A2h     = (_Float16*)p;  p += (size_t)NN * 128 * 2;  // GEMM2 out
    _Float16*  h2h     = (_Float16*)p;  p += (size_t)NN * 128 * 2;  // SpMM2 out
    _Float16*  A3h     = (_Float16*)p;  p += (size_t)NN * NC * 2;   // GEMM3 out
    _Float16*  Wt1     = (_Float16*)p;  p += (size_t)R1 * 2;
    _Float16*  Wt2     = (_Float16*)p;  p += (size_t)R2 * 2;
    _Float16*  Wt3     = (_Float16*)p;  p += (size_t)R3 * 2;

    const int T = 256;
    const int NB = (NN + 1023) / 1024;   // 49
    const int GB = (NN + 63) / 64;       // 782 row-blocks for the GEMMs

    // ---- preprocessing
    wconv3_k<<<(R1 + R2 + R3) / 256, T, 0, stream>>>(W1, W2, W3, Wt1, Wt2, Wt3);
    zero2_k<<<(NN + T - 1) / T, T, 0, stream>>>(rowcnt, fill);
    hist_k<<<(NE + T - 1) / T, T, 0, stream>>>(rows, rowcnt);
    dinv_k<<<(NN + T - 1) / T, T, 0, stream>>>(rowcnt, dinv);
    scan1_k<<<NB, 1024, 0, stream>>>(rowcnt, excl, bsum);
    scan2_k<<<1, 64, 0, stream>>>(bsum, NB);
    scan3_k<<<(NN + T - 1) / T, T, 0, stream>>>(excl, bsum, row_ptr);
    scatter_k<<<(NE + T - 1) / T, T, 0, stream>>>(rows, cols, dinv, row_ptr, fill, cw);

    // ---- layer 1: 512 -> 500
    {
        gemm1_k<<<GB, T, 0, stream>>>(x, Wt1, b1, A1h, NN);
        // two sequential feature-half passes (small per-pass gather footprint)
        spmm_f16_256_k<<<(NN + 3) / 4, T, 0, stream>>>(row_ptr, rowcnt, cw, dinv,
                                                       A1h, h1h, 0);
        spmm_f16_256_k<<<(NN + 3) / 4, T, 0, stream>>>(row_ptr, rowcnt, cw, dinv,
                                                       A1h + (size_t)NN * 256, h1h, 256);
    }
    // ---- layer 2: 500 -> 100
    {
        gemm_lds_k<128, 0, 512><<<dim3(GB, 1), T, 0, stream>>>(
            h1h, Wt2, b2, A2h, 128, NN, HH2);
        spmm_f16_100_k<<<(NN + 15) / 16, T, 0, stream>>>(row_ptr, rowcnt, cw,
                                                         dinv, A2h, h2h);
    }
    // ---- layer 3: 100 -> 16
    {
        gemm_lds_k<64, 0, 128><<<dim3(GB, 1), T, 0, stream>>>(
            h2h, Wt3, b3, A3h, NC, NN, NC);
        spmm3h_k<<<(NN + 127) / 128, T, 0, stream>>>(row_ptr, rowcnt, cw,
                                                     dinv, A3h, B3);
        tanh_softmax_k<<<(NN + T - 1) / T, T, 0, stream>>>(B3, out);
    }
}

// Round 6
// 530.420 us; speedup vs baseline: 1.0315x; 1.0315x over previous
//
#include <hip/hip_runtime.h>
#include <math.h>

#define NN  50000
#define FIN 512
#define HH1 500
#define HH2 100
#define NC  16
#define NE  800000
#define KD  512            // K-pad for layers 1/2

typedef __attribute__((ext_vector_type(4))) float    f32x4;
typedef __attribute__((ext_vector_type(4))) _Float16 f16x4;
typedef __attribute__((ext_vector_type(8))) _Float16 f16x8;
typedef __attribute__((ext_vector_type(8))) unsigned short u16x8;
typedef __attribute__((ext_vector_type(4))) unsigned short u16x4;

// ---------------- CSR build ----------------

__global__ void zero2_k(int* a, int* b) {
    int i = blockIdx.x * blockDim.x + threadIdx.x;
    if (i < NN) { a[i] = 0; b[i] = 0; }
}

__global__ void hist_k(const int* __restrict__ rows, int* __restrict__ rowcnt) {
    int i = blockIdx.x * blockDim.x + threadIdx.x;
    if (i < NE) atomicAdd(&rowcnt[rows[i]], 1);
}

__global__ void dinv_k(const int* __restrict__ rowcnt, float* __restrict__ dinv) {
    int i = blockIdx.x * blockDim.x + threadIdx.x;
    if (i < NN) dinv[i] = rsqrtf((float)(rowcnt[i] + 1));   // +1 self-loop
}

// hierarchical scan: 49 blocks x 1024 -> 1-wave scan of block sums -> add
__global__ __launch_bounds__(1024) void scan1_k(const int* __restrict__ cnt,
                                                int* __restrict__ excl,
                                                int* __restrict__ bsum) {
    __shared__ int s[1024];
    int t = threadIdx.x;
    int i = blockIdx.x * 1024 + t;
    int v = (i < NN) ? cnt[i] : 0;
    s[t] = v;
    __syncthreads();
    #pragma unroll
    for (int off = 1; off < 1024; off <<= 1) {
        int add = (t >= off) ? s[t - off] : 0;
        __syncthreads();
        s[t] += add;
        __syncthreads();
    }
    if (i < NN) excl[i] = s[t] - v;
    if (t == 1023) bsum[blockIdx.x] = s[1023];
}

__global__ void scan2_k(int* bsum, int nb) {   // 1 block, 64 threads
    int lane = threadIdx.x;
    int orig = (lane < nb) ? bsum[lane] : 0;
    int v = orig;
    #pragma unroll
    for (int off = 1; off < 64; off <<= 1) {
        int u = __shfl_up(v, off, 64);
        if (lane >= off) v += u;
    }
    if (lane < nb) bsum[lane] = v - orig;      // exclusive
}

__global__ void scan3_k(const int* __restrict__ excl, const int* __restrict__ bsum,
                        int* __restrict__ ptr) {
    int i = blockIdx.x * 256 + threadIdx.x;
    if (i < NN) ptr[i] = excl[i] + bsum[i >> 10];
}

// fused (col, w) edge record: one 8B store per edge instead of two scattered 4B
__global__ void scatter_k(const int* __restrict__ rows, const int* __restrict__ cols,
                          const float* __restrict__ dinv,
                          const int* __restrict__ row_ptr, int* __restrict__ fill,
                          int2* __restrict__ cw) {
    int e = blockIdx.x * blockDim.x + threadIdx.x;
    if (e >= NE) return;
    int r = rows[e], c = cols[e];
    int pos = row_ptr[r] + atomicAdd(&fill[r], 1);
    cw[pos] = make_int2(c, __float_as_int(dinv[r] * dinv[c]));
}

// ---------------- fused W pre-transpose to fp16 ----------------
// Wt1[512][512], Wt2[128][512], Wt3[128][128], zero-padded, n-major.

#define R1 (512 * 512)
#define R2 (128 * 512)
#define R3 (128 * 128)

__global__ void wconv3_k(const float* __restrict__ W1, const float* __restrict__ W2,
                         const float* __restrict__ W3, _Float16* __restrict__ Wt1,
                         _Float16* __restrict__ Wt2, _Float16* __restrict__ Wt3)
{
    int idx = blockIdx.x * 256 + threadIdx.x;
    if (idx < R1) {
        int n_ = idx >> 9, kk = idx & 511;
        float v = (n_ < HH1) ? W1[(size_t)kk * HH1 + n_] : 0.0f;
        Wt1[idx] = (_Float16)v;
    } else if (idx < R1 + R2) {
        int j = idx - R1;
        int n_ = j >> 9, kk = j & 511;
        float v = (kk < HH1 && n_ < HH2) ? W2[(size_t)kk * HH2 + n_] : 0.0f;
        Wt2[j] = (_Float16)v;
    } else if (idx < R1 + R2 + R3) {
        int j = idx - R1 - R2;
        int n_ = j >> 7, kk = j & 127;
        float v = (kk < HH2 && n_ < NC) ? W3[(size_t)kk * NC + n_] : 0.0f;
        Wt3[j] = (_Float16)v;
    }
}

// ---------------- async global->LDS helper ----------------

typedef unsigned int u32g;

__device__ __forceinline__ void g2l16(const void* g, void* l) {
    __builtin_amdgcn_global_load_lds(
        (const __attribute__((address_space(1))) u32g*)g,
        (__attribute__((address_space(3))) u32g*)l, 16, 0, 0);
}

// ---------------- GEMM1: 64x256 tile, fp32 A reg-staged (no cvtx pass) -----
// R4's proven gemm_lds<256,1> structure (70us, 0 bank conflicts) with the A
// operand read directly as fp32 (R5's verified reg-staging path):
//   - aload(s+2): global_load_dwordx4 x2, issued TWO K-steps ahead (~full
//     HBM latency of cover under two compute phases)
//   - bstage(s+1): global_load_lds 16B, one step ahead (Wt1 is L2-resident)
//   - astore(s+1): RNE fp32->fp16 convert + ds_write AFTER the MFMAs, into
//     the buffer all waves finished reading (guaranteed by the top barrier).
// LDS bytes produced are bit-identical to the R4 fp16 path (same swizzle
// involution, same RNE convert), so ds_read side and numerics are unchanged.
// LDS = 2*4KB (As) + 2*16KB (Bs) = 40KB -> 4 blocks/CU at ~80 VGPR.

__global__ __launch_bounds__(256, 4) void gemm1_k(
    const float* __restrict__ A, const _Float16* __restrict__ Wt,
    const float* __restrict__ bias, _Float16* __restrict__ Cb, int n)
{
    __shared__ __align__(16) _Float16 As[2][64 * 32];    // 4KB  x2
    __shared__ __align__(16) _Float16 Bs[2][256 * 32];   // 16KB x2

    int tid  = threadIdx.x;
    int lane = tid & 63;
    int w    = tid >> 6;
    int lr = lane & 15, q = lane >> 4;
    int row0 = blockIdx.x * 64;
    int col0 = blockIdx.y * 256;

    f32x4 acc[4][4];
    #pragma unroll
    for (int i = 0; i < 4; i++)
        #pragma unroll
        for (int j = 0; j < 4; j++) acc[i][j] = (f32x4){0.f, 0.f, 0.f, 0.f};

    // A staging: 64 rows x 4 fp16-16B-units; this thread owns one unit.
    int arr = tid >> 2, ac8 = tid & 3;
    int ac8s = ac8 ^ ((arr >> 1) & 3);                 // pre-swizzled source unit
    int gr = row0 + arr; if (gr >= n) gr = n - 1;      // clamp; row never stored
    const float* asrc = A + (size_t)gr * 512 + ac8s * 8;

    float4 pav[2][2];   // [k-step parity][lo/hi float4]

    auto aload = [&](int kt, int par) {
        pav[par][0] = *(const float4*)(asrc + kt);
        pav[par][1] = *(const float4*)(asrc + kt + 4);
    };
    auto astore = [&](int bf, int par) {
        float4 v0 = pav[par][0], v1 = pav[par][1];
        f16x8 h = {(_Float16)v0.x, (_Float16)v0.y, (_Float16)v0.z, (_Float16)v0.w,
                   (_Float16)v1.x, (_Float16)v1.y, (_Float16)v1.z, (_Float16)v1.w};
        *(f16x8*)&As[bf][tid * 8] = h;
    };
    auto bstage = [&](int kt, int bf) {
        #pragma unroll
        for (int i = 0; i < 4; i++) {
            int id = i * 256 + tid;
            int rr = id >> 2, c8 = id & 3;
            int c8s = c8 ^ ((rr >> 1) & 3);
            g2l16(Wt + (size_t)(col0 + rr) * 512 + kt + c8s * 8, &Bs[bf][id * 8]);
        }
    };

    // prologue: A(0),A(1) in regs; stage A(0)+B(0).
    aload(0, 0);
    aload(32, 1);
    bstage(0, 0);
    astore(0, 0);

    #pragma unroll
    for (int step = 0; step < 16; step++) {
        int bf = step & 1;
        __syncthreads();                    // drains bstage(bf) + publishes astore
        if (step + 2 < 16) aload((step + 2) * 32, bf);       // reuses freed parity
        if (step + 1 < 16) bstage((step + 1) * 32, bf ^ 1);

        f16x8 a[4], b[4];
        #pragma unroll
        for (int t = 0; t < 4; t++) {
            int row = t * 16 + lr;
            a[t] = *(const f16x8*)&As[bf][(row * 4 + (q ^ ((row >> 1) & 3))) * 8];
        }
        #pragma unroll
        for (int t = 0; t < 4; t++) {
            int row = w * 64 + t * 16 + lr;
            b[t] = *(const f16x8*)&Bs[bf][(row * 4 + (q ^ ((row >> 1) & 3))) * 8];
        }
        #pragma unroll
        for (int ti = 0; ti < 4; ti++)
            #pragma unroll
            for (int tj = 0; tj < 4; tj++)
                acc[ti][tj] = __builtin_amdgcn_mfma_f32_16x16x32_f16(
                    a[ti], b[tj], acc[ti][tj], 0, 0, 0);

        if (step + 1 < 16) astore(bf ^ 1, bf ^ 1);   // convert+write A(s+1)
    }

    // epilogue: chunk-major fp16 C  [col>>8][row][col&255]
    #pragma unroll
    for (int ti = 0; ti < 4; ti++) {
        #pragma unroll
        for (int tj = 0; tj < 4; tj++) {
            int col = col0 + w * 64 + tj * 16 + lr;
            bool valid = col < HH1;
            float bv = valid ? bias[col] : 0.0f;
            size_t cbase = (size_t)(col >> 8) * ((size_t)NN * 256) + (col & 255);
            #pragma unroll
            for (int p = 0; p < 4; p++) {
                int row = row0 + ti * 16 + q * 4 + p;
                if (row < n) {
                    float v = valid ? (acc[ti][tj][p] + bv) : 0.0f;
                    Cb[cbase + (size_t)row * 256] = (_Float16)v;
                }
            }
        }
    }
}

// ---------------- fp16 MFMA GEMM via global_load_lds (layers 2/3) ----------

template<int BCOLS, int COUT, int KK>
__global__ __launch_bounds__(256, 3) void gemm_lds_k(
    const _Float16* __restrict__ A,    // [n][KK] fp16
    const _Float16* __restrict__ Wt,   // [.][KK] fp16, n-major
    const float* __restrict__ bias, _Float16* __restrict__ Cb,
    int mpad, int n, int m)
{
    constexpr int NBF   = BCOLS / 64;   // B fragments per wave
    constexpr int WC    = BCOLS / 4;    // cols per wave
    constexpr int NSTEP = KK / 32;

    __shared__ __align__(16) _Float16 As[2][64 * 32];
    __shared__ __align__(16) _Float16 Bs[2][BCOLS * 32];

    int tid  = threadIdx.x;
    int lane = tid & 63;
    int w    = tid >> 6;
    int lr = lane & 15, q = lane >> 4;
    int row0 = blockIdx.x * 64;
    int col0 = blockIdx.y * BCOLS;

    f32x4 acc[4][NBF];
    #pragma unroll
    for (int i = 0; i < 4; i++)
        #pragma unroll
        for (int j = 0; j < NBF; j++) acc[i][j] = (f32x4){0.f, 0.f, 0.f, 0.f};

    auto stage = [&](int kt, int bf) {
        {   // A tile: 64 rows x 32 cols = 256 x 16B
            int rr = tid >> 2, c8 = tid & 3;
            int c8s = c8 ^ ((rr >> 1) & 3);             // pre-swizzled source
            int gr = row0 + rr; if (gr >= n) gr = n - 1; // clamp; row never stored
            g2l16(A + (size_t)gr * KK + kt + c8s * 8, &As[bf][tid * 8]);
        }
        #pragma unroll
        for (int i = 0; i < NBF; i++) {                 // B tile: BCOLS x 32
            int idx = i * 256 + tid;
            int rr = idx >> 2, c8 = idx & 3;
            int c8s = c8 ^ ((rr >> 1) & 3);
            g2l16(Wt + (size_t)(col0 + rr) * KK + kt + c8s * 8, &Bs[bf][idx * 8]);
        }
    };

    stage(0, 0);
    int bf = 0;
    #pragma unroll
    for (int step = 0; step < NSTEP; step++) {
        __syncthreads();                   // drains gload_lds for buf bf
        if (step + 1 < NSTEP) stage((step + 1) * 32, bf ^ 1);

        f16x8 a[4], b[NBF];
        #pragma unroll
        for (int t = 0; t < 4; t++) {
            int row = t * 16 + lr;
            a[t] = *(const f16x8*)&As[bf][(row * 4 + (q ^ ((row >> 1) & 3))) * 8];
        }
        #pragma unroll
        for (int t = 0; t < NBF; t++) {
            int row = w * WC + t * 16 + lr;
            b[t] = *(const f16x8*)&Bs[bf][(row * 4 + (q ^ ((row >> 1) & 3))) * 8];
        }
        #pragma unroll
        for (int ti = 0; ti < 4; ti++)
            #pragma unroll
            for (int tj = 0; tj < NBF; tj++)
                acc[ti][tj] = __builtin_amdgcn_mfma_f32_16x16x32_f16(
                    a[ti], b[tj], acc[ti][tj], 0, 0, 0);
        bf ^= 1;
    }

    #pragma unroll
    for (int ti = 0; ti < 4; ti++) {
        #pragma unroll
        for (int tj = 0; tj < NBF; tj++) {
            int col = col0 + w * WC + tj * 16 + lr;
            if (COUT == 0 && col >= mpad) continue;
            bool valid = col < m;
            float bv = valid ? bias[col] : 0.0f;
            #pragma unroll
            for (int p = 0; p < 4; p++) {
                int row = row0 + ti * 16 + q * 4 + p;
                if (row < n) {
                    float v = valid ? (acc[ti][tj][p] + bv) : 0.0f;
                    if (COUT == 1) {
                        size_t addr = (size_t)(col >> 8) * ((size_t)NN * 256)
                                    + (size_t)row * 256 + (col & 255);
                        Cb[addr] = (_Float16)v;
                    } else {
                        Cb[(size_t)row * mpad + col] = (_Float16)v;
                    }
                }
            }
        }
    }
}

// ---------------- fp16 mixed-precision FMA helpers ----------------

__device__ __forceinline__ void fma_mix8(float* acc, u16x8 v, float w) {
    union { u16x8 u; unsigned int d[4]; } t; t.u = v;
    #pragma unroll
    for (int k = 0; k < 4; k++) {
        asm("v_fma_mix_f32 %0, %1, %2, %0 op_sel:[0,0,0] op_sel_hi:[1,0,0]"
            : "+v"(acc[2 * k]) : "v"(t.d[k]), "v"(w));
        asm("v_fma_mix_f32 %0, %1, %2, %0 op_sel:[1,0,0] op_sel_hi:[1,0,0]"
            : "+v"(acc[2 * k + 1]) : "v"(t.d[k]), "v"(w));
    }
}

__device__ __forceinline__ void fma_mix4(float* acc, u16x4 v, float w) {
    union { u16x4 u; unsigned int d[2]; } t; t.u = v;
    #pragma unroll
    for (int k = 0; k < 2; k++) {
        asm("v_fma_mix_f32 %0, %1, %2, %0 op_sel:[0,0,0] op_sel_hi:[1,0,0]"
            : "+v"(acc[2 * k]) : "v"(t.d[k]), "v"(w));
        asm("v_fma_mix_f32 %0, %1, %2, %0 op_sel:[1,0,0] op_sel_hi:[1,0,0]"
            : "+v"(acc[2 * k + 1]) : "v"(t.d[k]), "v"(w));
    }
}

// ---------------- SpMM L1: feature-split gather (2 passes x 256 features) ----

__global__ __launch_bounds__(256) void spmm_f16_256_k(
    const int* __restrict__ row_ptr, const int* __restrict__ rowcnt,
    const int2* __restrict__ cw, const float* __restrict__ dinv,
    const _Float16* __restrict__ hc,   // chunk base: [NN][256]
    _Float16* __restrict__ outh, int fbase)
{
    int r = blockIdx.x * 4 + (threadIdx.x >> 6);
    int lane = threadIdx.x & 63;
    if (r >= NN) return;

    const u16x4* h4 = (const u16x4*)hc;   // row stride = 64 vec4

    float acc[4];
    #pragma unroll
    for (int i = 0; i < 4; i++) acc[i] = 0.f;

    float d = dinv[r];
    fma_mix4(acc, h4[(size_t)r * 64 + lane], d * d);   // self loop

    int beg = row_ptr[r], cnt = rowcnt[r];
    for (int base = 0; base < cnt; base += 64) {
        int m = (cnt - base < 64) ? (cnt - base) : 64;
        int2 vc = (lane < m) ? cw[beg + base + lane] : make_int2(0, 0);
        int P = (m + 7) & ~7;
        for (int j = 0; j < P; j += 8) {
            u16x4 vv[8]; float wl[8];
            #pragma unroll
            for (int u = 0; u < 8; u++) {
                int c  = __builtin_amdgcn_readlane(vc.x, j + u);
                int wb = __builtin_amdgcn_readlane(vc.y, j + u);
                wl[u] = __int_as_float(wb);
                vv[u] = h4[(size_t)c * 64 + lane];
            }
            #pragma unroll
            for (int u = 0; u < 8; u++) fma_mix4(acc, vv[u], wl[u]);
        }
    }

    int f0 = fbase + lane * 4;
    f16x4 o;
    #pragma unroll
    for (int i = 0; i < 4; i++)
        o[i] = (_Float16)((f0 + i < HH1) ? tanhf(acc[i]) : 0.0f);
    __builtin_nontemporal_store(o, (f16x4*)(outh + (size_t)r * KD + f0));
}

// ---------------- SpMM L2: fp16 gather (stride 128) -> fp16 out (stride 128) --

__global__ __launch_bounds__(256) void spmm_f16_100_k(
    const int* __restrict__ row_ptr, const int* __restrict__ rowcnt,
    const int2* __restrict__ cw, const float* __restrict__ dinv,
    const _Float16* __restrict__ hb, _Float16* __restrict__ outh)
{
    int r = blockIdx.x * 16 + (threadIdx.x >> 4);
    int lane = threadIdx.x & 15;
    if (r >= NN) return;

    const u16x8* h8 = (const u16x8*)hb;   // row stride = 16 vec8

    float acc[8];
    #pragma unroll
    for (int i = 0; i < 8; i++) acc[i] = 0.f;

    float d = dinv[r];
    fma_mix8(acc, h8[(size_t)r * 16 + lane], d * d);

    int beg = row_ptr[r], cnt = rowcnt[r];
    int j = 0;
    for (; j + 7 < cnt; j += 8) {
        int2  e[8];
        u16x8 v[8];
        #pragma unroll
        for (int u = 0; u < 8; u++) e[u] = cw[beg + j + u];
        #pragma unroll
        for (int u = 0; u < 8; u++) v[u] = h8[(size_t)e[u].x * 16 + lane];
        #pragma unroll
        for (int u = 0; u < 8; u++) fma_mix8(acc, v[u], __int_as_float(e[u].y));
    }
    for (; j < cnt; j++) {
        int2 e = cw[beg + j];
        fma_mix8(acc, h8[(size_t)e.x * 16 + lane], __int_as_float(e.y));
    }

    int f0 = lane * 8;
    f16x8 o;
    #pragma unroll
    for (int i = 0; i < 8; i++)
        o[i] = (_Float16)((f0 + i < HH2) ? tanhf(acc[i]) : 0.0f);
    __builtin_nontemporal_store(o, (f16x8*)(outh + (size_t)r * 128 + f0));
}

// ---------------- SpMM L3: fp16 gather (stride 16) -> fp32 out (stride 16) ----

__global__ __launch_bounds__(256) void spmm3h_k(
    const int* __restrict__ row_ptr, const int* __restrict__ rowcnt,
    const int2* __restrict__ cw, const float* __restrict__ dinv,
    const _Float16* __restrict__ hb, float* __restrict__ out)
{
    int r = blockIdx.x * 128 + (threadIdx.x >> 1);
    int lane = threadIdx.x & 1;
    if (r >= NN) return;

    const u16x8* h8 = (const u16x8*)hb;   // row stride = 2 vec8

    float acc[8];
    #pragma unroll
    for (int i = 0; i < 8; i++) acc[i] = 0.f;

    float d = dinv[r];
    fma_mix8(acc, h8[(size_t)r * 2 + lane], d * d);

    int beg = row_ptr[r], cnt = rowcnt[r];
    int j = 0;
    for (; j + 3 < cnt; j += 4) {
        int2  e0 = cw[beg + j],     e1 = cw[beg + j + 1];
        int2  e2 = cw[beg + j + 2], e3 = cw[beg + j + 3];
        u16x8 v0 = h8[(size_t)e0.x * 2 + lane];
        u16x8 v1 = h8[(size_t)e1.x * 2 + lane];
        u16x8 v2 = h8[(size_t)e2.x * 2 + lane];
        u16x8 v3 = h8[(size_t)e3.x * 2 + lane];
        fma_mix8(acc, v0, __int_as_float(e0.y));
        fma_mix8(acc, v1, __int_as_float(e1.y));
        fma_mix8(acc, v2, __int_as_float(e2.y));
        fma_mix8(acc, v3, __int_as_float(e3.y));
    }
    for (; j < cnt; j++) {
        int2 e = cw[beg + j];
        fma_mix8(acc, h8[(size_t)e.x * 2 + lane], __int_as_float(e.y));
    }

    float* o = out + (size_t)r * NC + lane * 8;
    f32x4 a0 = {acc[0], acc[1], acc[2], acc[3]};
    f32x4 a1 = {acc[4], acc[5], acc[6], acc[7]};
    __builtin_nontemporal_store(a0, (f32x4*)o);
    __builtin_nontemporal_store(a1, (f32x4*)(o + 4));
}

// final: tanh then softmax over 16 classes, one thread per row
__global__ void tanh_softmax_k(const float* __restrict__ in, float* __restrict__ out) {
    int r = blockIdx.x * blockDim.x + threadIdx.x;
    if (r >= NN) return;
    float v[NC];
    float mx = -1e30f;
    #pragma unroll
    for (int j = 0; j < NC; j++) {
        v[j] = tanhf(in[r * NC + j]);
        mx = fmaxf(mx, v[j]);
    }
    float s = 0.0f;
    #pragma unroll
    for (int j = 0; j < NC; j++) { v[j] = expf(v[j] - mx); s += v[j]; }
    float inv = 1.0f / s;
    #pragma unroll
    for (int j = 0; j < NC; j++) out[r * NC + j] = v[j] * inv;
}

// ---------------- launch ----------------

extern "C" void kernel_launch(void* const* d_in, const int* in_sizes, int n_in,
                              void* d_out, int out_size, void* d_ws, size_t ws_size,
                              hipStream_t stream)
{
    const float* x  = (const float*)d_in[0];
    const int*   ei = (const int*)d_in[1];
    const float* W1 = (const float*)d_in[2];
    const float* b1 = (const float*)d_in[3];
    const float* W2 = (const float*)d_in[4];
    const float* b2 = (const float*)d_in[5];
    const float* W3 = (const float*)d_in[6];
    const float* b3 = (const float*)d_in[7];
    float* out = (float*)d_out;

    const int* rows = ei;
    const int* cols = ei + NE;

    char* p = (char*)d_ws;
    float*     dinv    = (float*)p;     p += (size_t)NN * 4;
    int*       rowcnt  = (int*)p;       p += (size_t)NN * 4;
    int*       row_ptr = (int*)p;       p += (size_t)NN * 4;
    int*       fill    = (int*)p;       p += (size_t)NN * 4;
    int*       excl    = (int*)p;       p += (size_t)NN * 4;
    int*       bsum    = (int*)p;       p += (size_t)256 * 4;
    int2*      cw      = (int2*)p;      p += (size_t)NE * 8;    // fused (col, w)
    float*     B3      = (float*)p;     p += (size_t)NN * NC * 4;   // SpMM3 out
    _Float16*  A1h     = (_Float16*)p;  p += (size_t)NN * KD * 2;   // GEMM1 out, chunked [2][NN][256]
    _Float16*  h1h     = (_Float16*)p;  p += (size_t)NN * KD * 2;   // SpMM1 out, linear [NN][512]
    _Float16*  A2h     = (_Float16*)p;  p += (size_t)NN * 128 * 2;  // GEMM2 out
    _Float16*  h2h     = (_Float16*)p;  p += (size_t)NN * 128 * 2;  // SpMM2 out
    _Float16*  A3h     = (_Float16*)p;  p += (size_t)NN * NC * 2;   // GEMM3 out
    _Float16*  Wt1     = (_Float16*)p;  p += (size_t)R1 * 2;
    _Float16*  Wt2     = (_Float16*)p;  p += (size_t)R2 * 2;
    _Float16*  Wt3     = (_Float16*)p;  p += (size_t)R3 * 2;

    const int T = 256;
    const int NB = (NN + 1023) / 1024;   // 49
    const int GB = (NN + 63) / 64;       // 782 row-blocks for the GEMMs

    // ---- preprocessing
    wconv3_k<<<(R1 + R2 + R3) / 256, T, 0, stream>>>(W1, W2, W3, Wt1, Wt2, Wt3);
    zero2_k<<<(NN + T - 1) / T, T, 0, stream>>>(rowcnt, fill);
    hist_k<<<(NE + T - 1) / T, T, 0, stream>>>(rows, rowcnt);
    dinv_k<<<(NN + T - 1) / T, T, 0, stream>>>(rowcnt, dinv);
    scan1_k<<<NB, 1024, 0, stream>>>(rowcnt, excl, bsum);
    scan2_k<<<1, 64, 0, stream>>>(bsum, NB);
    scan3_k<<<(NN + T - 1) / T, T, 0, stream>>>(excl, bsum, row_ptr);
    scatter_k<<<(NE + T - 1) / T, T, 0, stream>>>(rows, cols, dinv, row_ptr, fill, cw);

    // ---- layer 1: 512 -> 500
    {
        gemm1_k<<<dim3(GB, 2), T, 0, stream>>>(x, Wt1, b1, A1h, NN);
        // two sequential feature-half passes (small per-pass gather footprint)
        spmm_f16_256_k<<<(NN + 3) / 4, T, 0, stream>>>(row_ptr, rowcnt, cw, dinv,
                                                       A1h, h1h, 0);
        spmm_f16_256_k<<<(NN + 3) / 4, T, 0, stream>>>(row_ptr, rowcnt, cw, dinv,
                                                       A1h + (size_t)NN * 256, h1h, 256);
    }
    // ---- layer 2: 500 -> 100
    {
        gemm_lds_k<128, 0, 512><<<dim3(GB, 1), T, 0, stream>>>(
            h1h, Wt2, b2, A2h, 128, NN, HH2);
        spmm_f16_100_k<<<(NN + 15) / 16, T, 0, stream>>>(row_ptr, rowcnt, cw,
                                                         dinv, A2h, h2h);
    }
    // ---- layer 3: 100 -> 16
    {
        gemm_lds_k<64, 0, 128><<<dim3(GB, 1), T, 0, stream>>>(
            h2h, Wt3, b3, A3h, NC, NN, NC);
        spmm3h_k<<<(NN + 127) / 128, T, 0, stream>>>(row_ptr, rowcnt, cw,
                                                     dinv, A3h, B3);
        tanh_softmax_k<<<(NN + T - 1) / T, T, 0, stream>>>(B3, out);
    }
}